// Round 12
// baseline (129.135 us; speedup 1.0000x reference)
//
#include <hip/hip_runtime.h>
#include <hip/hip_bf16.h>

#define D_MODEL 1024
#define S_LEN   2048
#define NBATCH  2
#define NHEADS  16
#define HDIM    64
#define DQKV    3072   // 3 * D_MODEL

typedef short bf16x8 __attribute__((ext_vector_type(8)));
typedef float f32x4  __attribute__((ext_vector_type(4)));
typedef float f32x16 __attribute__((ext_vector_type(16)));
typedef unsigned int u32;

// ---------------------------------------------------------------------------
__device__ __forceinline__ unsigned short bf16_rne(float f) {
    unsigned u = __float_as_uint(f);
    return (unsigned short)((u + 0x7FFFu + ((u >> 16) & 1u)) >> 16);
}

// Fused cast: x (4M f32) | w_qkv (3M) | w_out (1M) -> contiguous bf16 ws
__global__ __launch_bounds__(256) void cast_all_bf16(
    const float* __restrict__ x, const float* __restrict__ wq,
    const float* __restrict__ wo, unsigned short* __restrict__ out)
{
    const int n4x = 1048576, n4q = 786432;           // vec4 counts: x, w_qkv
    const int total = n4x + n4q + 262144;
    int i = blockIdx.x * blockDim.x + threadIdx.x;
    const int stride = gridDim.x * blockDim.x;
    for (; i < total; i += stride) {
        float4 v;
        if (i < n4x)            v = ((const float4*)x)[i];
        else if (i < n4x + n4q) v = ((const float4*)wq)[i - n4x];
        else                    v = ((const float4*)wo)[i - n4x - n4q];
        ((ushort4*)out)[i] = make_ushort4(bf16_rne(v.x), bf16_rne(v.y),
                                          bf16_rne(v.z), bf16_rne(v.w));
    }
}

__device__ __forceinline__ void gld_lds16(const unsigned short* g, unsigned short* l) {
    __builtin_amdgcn_global_load_lds(
        (const __attribute__((address_space(1))) unsigned int*)g,
        (__attribute__((address_space(3))) unsigned int*)l, 16, 0, 0);
}

// Swizzled LDS fragment read: rows of 64 ushort (128B), byte ^= (row&7)<<4.
// Pairs with inverse-swizzled global_load_lds source (same involution).
__device__ __forceinline__ bf16x8 lds_frag(const unsigned short* base, int row, int e8) {
    int byte = (row << 7) + (e8 << 4);
    byte ^= (row & 7) << 4;
    return *(const bf16x8*)((const char*)base + byte);
}

// ---------------------------------------------------------------------------
// bf16 GEMM core: C_tile = A[M][K] * B[N][K]^T. 128x128 tile, BK=64, 4 waves,
// 32 MFMA (16x16x32) per K-tile. Double-buffered LDS (2 x 32KB): STAGE(t+1)
// issued before compute(t), single barrier per tile. XOR-swizzled rows.
// ---------------------------------------------------------------------------
#define GEMM_CORE(A_, B_, K_)                                                  \
    __shared__ unsigned short sA[2][128 * 64];                                 \
    __shared__ unsigned short sB[2][128 * 64];                                 \
    const int tid  = threadIdx.x;                                              \
    const int lane = tid & 63;                                                 \
    const int wid  = tid >> 6;                                                 \
    const int bm = blockIdx.y * 128, bn = blockIdx.x * 128;                    \
    const int wr = (wid >> 1) * 64, wc = (wid & 1) * 64;                       \
    const int half = wid & 1;                                                  \
    const unsigned short* gsrc = (wid < 2) ? A_ : B_;                          \
    unsigned short* ldst0 = ((wid < 2) ? sA[0] : sB[0]) + half * 4096;         \
    unsigned short* ldst1 = ((wid < 2) ? sA[1] : sB[1]) + half * 4096;         \
    const int brow = ((wid < 2) ? bm : bn) + half * 64;                        \
    const int r8_  = lane >> 3;                                                \
    const int colb_ = ((lane & 7) ^ r8_) << 3;                                 \
    const size_t rowbase = (size_t)(brow + r8_) * K_ + colb_;                  \
    f32x4 acc[4][4];                                                           \
    _Pragma("unroll")                                                          \
    for (int m = 0; m < 4; ++m)                                                \
        _Pragma("unroll")                                                      \
        for (int n = 0; n < 4; ++n)                                            \
            acc[m][n] = f32x4{0.f, 0.f, 0.f, 0.f};                             \
    {                                                                          \
        const unsigned short* g = gsrc + rowbase;                              \
        _Pragma("unroll")                                                      \
        for (int c = 0; c < 8; ++c)                                            \
            gld_lds16(g + (size_t)c * 8 * K_, ldst0 + c * 512);                \
    }                                                                          \
    __syncthreads();                                                           \
    int pb = 0;                                                                \
    for (int k0 = 0; k0 < K_; k0 += 64) {                                      \
        if (k0 + 64 < K_) {                                                    \
            const unsigned short* g = gsrc + rowbase + k0 + 64;                \
            unsigned short* ld = pb ? ldst0 : ldst1;                           \
            _Pragma("unroll")                                                  \
            for (int c = 0; c < 8; ++c)                                        \
                gld_lds16(g + (size_t)c * 8 * K_, ld + c * 512);               \
        }                                                                      \
        const unsigned short* cA = pb ? sA[1] : sA[0];                         \
        const unsigned short* cB = pb ? sB[1] : sB[0];                         \
        _Pragma("unroll")                                                      \
        for (int ks2 = 0; ks2 < 2; ++ks2) {                                    \
            const int e8 = (lane >> 4) + ks2 * 4;                              \
            bf16x8 a[4], b[4];                                                 \
            _Pragma("unroll")                                                  \
            for (int m = 0; m < 4; ++m)                                        \
                a[m] = lds_frag(cA, wr + m * 16 + (lane & 15), e8);            \
            _Pragma("unroll")                                                  \
            for (int n = 0; n < 4; ++n)                                        \
                b[n] = lds_frag(cB, wc + n * 16 + (lane & 15), e8);            \
            _Pragma("unroll")                                                  \
            for (int m = 0; m < 4; ++m)                                        \
                _Pragma("unroll")                                              \
                for (int n = 0; n < 4; ++n)                                    \
                    acc[m][n] = __builtin_amdgcn_mfma_f32_16x16x32_bf16(       \
                        a[m], b[n], acc[m][n], 0, 0, 0);                       \
        }                                                                      \
        __syncthreads();                                                       \
        pb ^= 1;                                                               \
    }

// ---------------------------------------------------------------------------
// out-projection: 64x128 tile (M-split) -> 512 blocks, LDS 48KB -> 3 blk/CU.
// 4 waves 2(M)x2(N); each wave 32x64 output = acc[2][4]. Identical MFMA
// ordering per output element as the 128x128 core (bit-identical result).
// ---------------------------------------------------------------------------
__global__ __launch_bounds__(256) void gemm_mfma_out(
    const unsigned short* __restrict__ A, const unsigned short* __restrict__ B,
    const float* __restrict__ bias, float* __restrict__ C, int M, int N, int K)
{
    __shared__ unsigned short sA[2][64 * 64];    // 2 x 8KB
    __shared__ unsigned short sB[2][128 * 64];   // 2 x 16KB

    const int tid  = threadIdx.x;
    const int lane = tid & 63;
    const int wid  = tid >> 6;
    const int bm = blockIdx.y * 64, bn = blockIdx.x * 128;
    const int wr = (wid >> 1) * 32, wc = (wid & 1) * 64;
    const int r8   = lane >> 3;
    const int colb = ((lane & 7) ^ r8) << 3;

    f32x4 acc[2][4];
    #pragma unroll
    for (int m = 0; m < 2; ++m)
        #pragma unroll
        for (int n = 0; n < 4; ++n)
            acc[m][n] = f32x4{0.f, 0.f, 0.f, 0.f};

    // 24 chunks of 1KB (A: 0-7, B: 8-23); wave w stages chunks [6w, 6w+6)
    #define OSTAGE(buf, k0)                                                         \
        do {                                                                        \
            _Pragma("unroll")                                                       \
            for (int ci = 0; ci < 6; ++ci) {                                        \
                const int c = wid * 6 + ci;                                         \
                if (c < 8)                                                          \
                    gld_lds16(A + (size_t)(bm + c * 8 + r8) * K + colb + (k0),      \
                              &sA[buf][c * 512]);                                   \
                else                                                                \
                    gld_lds16(B + (size_t)(bn + (c - 8) * 8 + r8) * K + colb + (k0),\
                              &sB[buf][(c - 8) * 512]);                             \
            }                                                                       \
        } while (0)

    OSTAGE(0, 0);
    __syncthreads();
    int pb = 0;
    for (int k0 = 0; k0 < K; k0 += 64) {
        if (k0 + 64 < K) OSTAGE(pb ^ 1, k0 + 64);
        const unsigned short* cA = sA[pb];
        const unsigned short* cB = sB[pb];
        #pragma unroll
        for (int ks2 = 0; ks2 < 2; ++ks2) {
            const int e8 = (lane >> 4) + ks2 * 4;
            bf16x8 a[2], b[4];
            #pragma unroll
            for (int m = 0; m < 2; ++m)
                a[m] = lds_frag(cA, wr + m * 16 + (lane & 15), e8);
            #pragma unroll
            for (int n = 0; n < 4; ++n)
                b[n] = lds_frag(cB, wc + n * 16 + (lane & 15), e8);
            #pragma unroll
            for (int m = 0; m < 2; ++m)
                #pragma unroll
                for (int n = 0; n < 4; ++n)
                    acc[m][n] = __builtin_amdgcn_mfma_f32_16x16x32_bf16(
                        a[m], b[n], acc[m][n], 0, 0, 0);
        }
        __syncthreads();
        pb ^= 1;
    }
    #undef OSTAGE

    #pragma unroll
    for (int n = 0; n < 4; ++n) {
        const int col = bn + wc + n * 16 + (lane & 15);
        const float bv = bias[col];
        #pragma unroll
        for (int m = 0; m < 2; ++m) {
            const int row0 = bm + wr + m * 16 + (lane >> 4) * 4;
            #pragma unroll
            for (int j = 0; j < 4; ++j)
                C[(size_t)(row0 + j) * N + col] = acc[m][n][j] + bv;
        }
    }
}

// QKV projection: scatter epilogue into single bf16 planes
//   Q [b,h,s,d] pre-scaled by log2(e)/8, K [b,h,s,d], Vt [b,h,d,s]
// V-class stores packed: 4 consecutive s -> one ushort4.
__global__ __launch_bounds__(256) void gemm_mfma_qkv(
    const unsigned short* __restrict__ A, const unsigned short* __restrict__ B,
    const float* __restrict__ bias,
    unsigned short* __restrict__ Qs, unsigned short* __restrict__ Ks,
    unsigned short* __restrict__ Vt, int M, int N, int K)
{
    GEMM_CORE(A, B, K)
    #pragma unroll
    for (int n = 0; n < 4; ++n) {
        const int col = bn + wc + n * 16 + (lane & 15);
        const unsigned head = (unsigned)col / 192u;
        const int c = col - (int)head * 192;
        const int cls = c >> 6;                    // 0=q 1=k 2=v (uniform per n)
        const float bv = bias[col];
        #pragma unroll
        for (int m = 0; m < 4; ++m) {
            const int row0 = bm + wr + m * 16 + (lane >> 4) * 4;
            if (cls == 2) {
                const int bb = row0 >> 11, ss = row0 & 2047;
                unsigned short vv[4];
                #pragma unroll
                for (int j = 0; j < 4; ++j) vv[j] = bf16_rne(acc[m][n][j] + bv);
                *(ushort4*)&Vt[((size_t)(bb * NHEADS + head) * HDIM + (c - 128)) * S_LEN + ss] =
                    make_ushort4(vv[0], vv[1], vv[2], vv[3]);
            } else {
                #pragma unroll
                for (int j = 0; j < 4; ++j) {
                    const int row = row0 + j;
                    const int bb = row >> 11, ss = row & 2047;
                    float val = acc[m][n][j] + bv;
                    if (cls == 0) val *= 0.18033688011110918f;  // (1/8)*log2(e)
                    const size_t idx = ((size_t)(bb * NHEADS + head) * S_LEN + ss) * HDIM + (c & 63);
                    if (cls == 0) Qs[idx] = bf16_rne(val); else Ks[idx] = bf16_rne(val);
                }
            }
        }
    }
}

// ---------------------------------------------------------------------------
// Full-bf16 MFMA flash attention, kv-split, double-buffered. PROVEN R7/R10
// numerics: online max (tree), defer-max THR=8, exp2-domain softmax
// (Q pre-scaled by log2e/8), l via mfma(ones,P), m-weighted parity merge.
// Grid: 512 blocks x 8 waves; par=wid>>2 kv parity; wq=wid&3 owns 32 q-cols.
// ---------------------------------------------------------------------------
__global__ __launch_bounds__(512) void attn_mfma_kernel(
    const unsigned short* __restrict__ Qs, const unsigned short* __restrict__ Ks,
    const unsigned short* __restrict__ Vt, unsigned short* __restrict__ ob)
{
    __shared__ unsigned short smem[2][2][2][4096];   // [buf][par][cls][64*64]

    const int tid  = threadIdx.x;
    const int lane = tid & 63;
    const int wid  = tid >> 6;         // 0..7
    const int wq   = wid & 3;          // q sub-tile (32 cols)
    const int par  = wid >> 2;         // kv parity
    const int h    = lane >> 5;        // k-octet half
    const int qcol = lane & 31;

    // XCD-chunked remap: 512 blocks, XCD = bid%8 gets a contiguous 64-chunk
    const int bid = blockIdx.x;
    const int lb  = (bid & 7) * 64 + (bid >> 3);
    const int qt  = lb & 15;
    const int bh  = lb >> 4;
    const int q0  = qt * 128 + wq * 32;

    // ---- Q fragments in registers (pre-scaled at GEMM1) ----
    bf16x8 qf[4];
    {
        const unsigned short* qr = Qs + ((size_t)bh * S_LEN + q0 + qcol) * HDIM + h * 8;
        #pragma unroll
        for (int ks = 0; ks < 4; ++ks) qf[ks] = *(const bf16x8*)(qr + ks * 16);
    }

    // ones A-operand for the l-sum MFMA (bf16 1.0 = 0x3F80)
    bf16x8 onesv;
    #pragma unroll
    for (int i = 0; i < 8; ++i) onesv[i] = (short)0x3F80;

    // ---- staging: wave stages half a plane (4KB = 4 chunks) ----
    const unsigned short* gKV = (wq < 2) ? Ks : Vt;
    const int cls   = wq >> 1;                       // 0=K, 1=V
    const int cbase = (wq & 1) * 4;                  // chunk range
    const int r8    = lane >> 3;                     // row within 8-row chunk
    const int colb  = ((lane & 7) ^ r8) << 3;        // inverse-swizzled col

    float m_run = -1e30f;
    f32x16 accO[2];
    f32x16 accL;
    #pragma unroll
    for (int r = 0; r < 16; ++r) { accO[0][r] = 0.0f; accO[1][r] = 0.0f; accL[r] = 0.0f; }

    #define STAGE(buf, kt)                                                          \
        do {                                                                        \
            unsigned short* pl_ = &smem[buf][par][cls][0];                          \
            if (cls == 0) {                                                         \
                const unsigned short* g_ = gKV + ((size_t)bh * S_LEN + (kt) + r8) * HDIM + colb; \
                _Pragma("unroll")                                                   \
                for (int c_ = 0; c_ < 4; ++c_)                                      \
                    gld_lds16(g_ + (size_t)(cbase + c_) * 8 * HDIM,                 \
                              pl_ + (cbase + c_) * 512);                            \
            } else {                                                                \
                const unsigned short* g_ = gKV + ((size_t)bh * HDIM + r8) * S_LEN + (kt) + colb; \
                _Pragma("unroll")                                                   \
                for (int c_ = 0; c_ < 4; ++c_)                                      \
                    gld_lds16(g_ + (size_t)(cbase + c_) * 8 * S_LEN,                \
                              pl_ + (cbase + c_) * 512);                            \
            }                                                                       \
        } while (0)

    STAGE(0, par * 64);
    __syncthreads();

    int cur = 0;
    for (int it = 0; it < S_LEN / 128; ++it) {       // 16 iterations
        if (it + 1 < S_LEN / 128) STAGE(cur ^ 1, (it + 1) * 128 + par * 64);

        const unsigned short* cK = &smem[cur][par][0][0];
        const unsigned short* cV = &smem[cur][par][1][0];

        // ---- S^T = K . Q^T : accS[mm] is 32kv x 32q, lane owns q=qcol ----
        f32x16 accS[2];
        #pragma unroll
        for (int r = 0; r < 16; ++r) { accS[0][r] = 0.0f; accS[1][r] = 0.0f; }

        __builtin_amdgcn_s_setprio(1);
        #pragma unroll
        for (int ks = 0; ks < 4; ++ks) {
            const int e8 = ks * 2 + h;
            #pragma unroll
            for (int mm = 0; mm < 2; ++mm) {
                bf16x8 ak = lds_frag(cK, mm * 32 + qcol, e8);
                accS[mm] = __builtin_amdgcn_mfma_f32_32x32x16_bf16(ak, qf[ks], accS[mm], 0, 0, 0);
            }
        }
        __builtin_amdgcn_s_setprio(0);

        // ---- online softmax (exp2 domain): max tree, defer-max, in-place exp
        float t16[16];
        #pragma unroll
        for (int i = 0; i < 16; ++i) t16[i] = fmaxf(accS[0][i], accS[1][i]);
        float t8[8];
        #pragma unroll
        for (int i = 0; i < 8; ++i) t8[i] = fmaxf(t16[i], t16[i + 8]);
        float t4[4];
        #pragma unroll
        for (int i = 0; i < 4; ++i) t4[i] = fmaxf(t8[i], t8[i + 4]);
        float mx = fmaxf(fmaxf(t4[0], t4[1]), fmaxf(t4[2], t4[3]));
        mx = fmaxf(mx, __shfl_xor(mx, 32));

        if (!__all(mx <= m_run + 8.0f)) {
            const float mnew = fmaxf(m_run, mx);
            const float corr = __builtin_amdgcn_exp2f(m_run - mnew);
            m_run = mnew;
            #pragma unroll
            for (int r = 0; r < 16; ++r) {
                accO[0][r] *= corr; accO[1][r] *= corr; accL[r] *= corr;
            }
        }

        #pragma unroll
        for (int mm = 0; mm < 2; ++mm)
            #pragma unroll
            for (int r = 0; r < 16; ++r)
                accS[mm][r] = __builtin_amdgcn_exp2f(accS[mm][r] - m_run);

        // ---- P^T -> bf16 B-fragments (cvt_pk + shfl_xor(32)); PV + l-MFMA --
        const bool hib = (h != 0);
        #pragma unroll
        for (int mm = 0; mm < 2; ++mm) {
            u32 wh_[8], sh_[8];
            #pragma unroll
            for (int i = 0; i < 8; ++i) {
                const float pe = accS[mm][2 * i], po = accS[mm][2 * i + 1];
                asm("v_cvt_pk_bf16_f32 %0, %1, %2" : "=v"(wh_[i]) : "v"(pe), "v"(po));
            }
            #pragma unroll
            for (int i = 0; i < 8; ++i) sh_[i] = __shfl_xor(wh_[i], 32);
            #pragma unroll
            for (int cc = 0; cc < 2; ++cc) {
                const int b0 = cc * 4;
                union { u32 w[4]; bf16x8 v; } uh;
                uh.w[0] = hib ? sh_[b0 + 2] : wh_[b0 + 0];
                uh.w[1] = hib ? sh_[b0 + 3] : wh_[b0 + 1];
                uh.w[2] = hib ? wh_[b0 + 2] : sh_[b0 + 0];
                uh.w[3] = hib ? wh_[b0 + 3] : sh_[b0 + 1];
                const int e8 = (mm * 2 + cc) * 2 + h;   // kv octet
                bf16x8 vf0 = lds_frag(cV, qcol, e8);
                bf16x8 vf1 = lds_frag(cV, 32 + qcol, e8);
                accO[0] = __builtin_amdgcn_mfma_f32_32x32x16_bf16(vf0, uh.v, accO[0], 0, 0, 0);
                accO[1] = __builtin_amdgcn_mfma_f32_32x32x16_bf16(vf1, uh.v, accO[1], 0, 0, 0);
                accL    = __builtin_amdgcn_mfma_f32_32x32x16_bf16(onesv, uh.v, accL, 0, 0, 0);
            }
        }

        __syncthreads();   // cur reads done + next stage (vmcnt) drained
        cur ^= 1;
    }
    #undef STAGE

    const float l_run = accL[0];   // all 16 components identical

    // ---- merge parity pair states via LDS, then epilogue (par 0 writes) ----
    float* mbuf = (float*)&smem[0][0][0][0];
    if (par == 1) {
        float* dst = mbuf + ((size_t)(wq * 64 + lane)) * 35;  // stride 35: conflict-free
        #pragma unroll
        for (int mdc = 0; mdc < 2; ++mdc)
            #pragma unroll
            for (int r = 0; r < 16; ++r) dst[mdc * 16 + r] = accO[mdc][r];
        dst[32] = m_run;
        dst[33] = l_run;
    }
    __syncthreads();
    if (par == 0) {
        const float* src = mbuf + ((size_t)(wq * 64 + lane)) * 35;
        const float m2 = src[32], l2 = src[33];
        const float mt = fmaxf(m_run, m2);
        const float w1 = __builtin_amdgcn_exp2f(m_run - mt);
        const float w2 = __builtin_amdgcn_exp2f(m2 - mt);
        const float inv = 1.0f / (l_run * w1 + l2 * w2);

        const int bb = bh >> 4, hh = bh & 15;
        const int ss = q0 + qcol;
        unsigned short* po = ob + ((size_t)(bb * S_LEN + ss)) * D_MODEL + hh * HDIM;
        #pragma unroll
        for (int mdc = 0; mdc < 2; ++mdc)
            #pragma unroll
            for (int r = 0; r < 16; r += 2) {
                const int d = mdc * 32 + (r & 3) + 8 * (r >> 2) + 4 * h;
                const float v0 = (accO[mdc][r]     * w1 + src[mdc * 16 + r]     * w2) * inv;
                const float v1 = (accO[mdc][r + 1] * w1 + src[mdc * 16 + r + 1] * w2) * inv;
                *(u32*)(po + d) = ((u32)bf16_rne(v1) << 16) | bf16_rne(v0);
            }
    }
}

// ---------------------------------------------------------------------------
extern "C" void kernel_launch(void* const* d_in, const int* in_sizes, int n_in,
                              void* d_out, int out_size, void* d_ws, size_t ws_size,
                              hipStream_t stream)
{
    const float* x     = (const float*)d_in[0];
    const float* w_qkv = (const float*)d_in[1];
    const float* b_qkv = (const float*)d_in[2];
    const float* w_out = (const float*)d_in[3];
    const float* b_out = (const float*)d_in[4];
    float* out = (float*)d_out;

    const int M = NBATCH * S_LEN;  // 4096
    const size_t PL = (size_t)32 * S_LEN * HDIM;   // 4,194,304 elems

    // ws layout (50.3 MB of >= 67 MB). xb/wqb/wob contiguous (fused cast).
    unsigned short* xb  = (unsigned short*)d_ws;           // 4M elems
    unsigned short* wqb = xb  + PL;                        // 3M
    unsigned short* wob = wqb + (size_t)DQKV * D_MODEL;    // 1M
    unsigned short* Qs  = wob + (size_t)D_MODEL * D_MODEL; // 4M
    unsigned short* Ks  = Qs  + PL;
    unsigned short* Vt  = Ks  + PL;
    unsigned short* aob = Vt  + PL;                        // 4M

    dim3 blk(256);
    cast_all_bf16<<<1024, blk, 0, stream>>>(x, w_qkv, w_out, xb);

    gemm_mfma_qkv<<<dim3(DQKV / 128, M / 128), blk, 0, stream>>>(
        xb, wqb, b_qkv, Qs, Ks, Vt, M, DQKV, D_MODEL);

    attn_mfma_kernel<<<dim3(512), dim3(512), 0, stream>>>(Qs, Ks, Vt, aob);

    gemm_mfma_out<<<dim3(D_MODEL / 128, M / 64), blk, 0, stream>>>(
        aob, wob, b_out, out, M, D_MODEL, D_MODEL);
}

// Round 13
// 125.790 us; speedup vs baseline: 1.0266x; 1.0266x over previous
//
#include <hip/hip_runtime.h>
#include <hip/hip_bf16.h>

#define D_MODEL 1024
#define S_LEN   2048
#define NBATCH  2
#define NHEADS  16
#define HDIM    64
#define DQKV    3072   // 3 * D_MODEL

typedef short bf16x8 __attribute__((ext_vector_type(8)));
typedef float f32x4  __attribute__((ext_vector_type(4)));
typedef float f32x16 __attribute__((ext_vector_type(16)));
typedef unsigned int u32;

// ---------------------------------------------------------------------------
__device__ __forceinline__ unsigned short bf16_rne(float f) {
    unsigned u = __float_as_uint(f);
    return (unsigned short)((u + 0x7FFFu + ((u >> 16) & 1u)) >> 16);
}

// Fused cast: x (4M f32) | w_qkv (3M) | w_out (1M) -> contiguous bf16 ws
__global__ __launch_bounds__(256) void cast_all_bf16(
    const float* __restrict__ x, const float* __restrict__ wq,
    const float* __restrict__ wo, unsigned short* __restrict__ out)
{
    const int n4x = 1048576, n4q = 786432;           // vec4 counts: x, w_qkv
    const int total = n4x + n4q + 262144;
    int i = blockIdx.x * blockDim.x + threadIdx.x;
    const int stride = gridDim.x * blockDim.x;
    for (; i < total; i += stride) {
        float4 v;
        if (i < n4x)            v = ((const float4*)x)[i];
        else if (i < n4x + n4q) v = ((const float4*)wq)[i - n4x];
        else                    v = ((const float4*)wo)[i - n4x - n4q];
        ((ushort4*)out)[i] = make_ushort4(bf16_rne(v.x), bf16_rne(v.y),
                                          bf16_rne(v.z), bf16_rne(v.w));
    }
}

__device__ __forceinline__ void gld_lds16(const unsigned short* g, unsigned short* l) {
    __builtin_amdgcn_global_load_lds(
        (const __attribute__((address_space(1))) unsigned int*)g,
        (__attribute__((address_space(3))) unsigned int*)l, 16, 0, 0);
}

// Swizzled LDS fragment read: rows of 64 ushort (128B), byte ^= (row&7)<<4.
// Pairs with inverse-swizzled global_load_lds source (same involution).
__device__ __forceinline__ bf16x8 lds_frag(const unsigned short* base, int row, int e8) {
    int byte = (row << 7) + (e8 << 4);
    byte ^= (row & 7) << 4;
    return *(const bf16x8*)((const char*)base + byte);
}

// ---------------------------------------------------------------------------
// bf16 GEMM core: C_tile = A[M][K] * B[N][K]^T. 128x128 tile, BK=64, 4 waves,
// 32 MFMA (16x16x32) per K-tile. Double-buffered LDS (2 x 32KB): STAGE(t+1)
// issued before compute(t), single barrier per tile. XOR-swizzled rows.
// ---------------------------------------------------------------------------
#define GEMM_CORE(A_, B_, K_)                                                  \
    __shared__ unsigned short sA[2][128 * 64];                                 \
    __shared__ unsigned short sB[2][128 * 64];                                 \
    const int tid  = threadIdx.x;                                              \
    const int lane = tid & 63;                                                 \
    const int wid  = tid >> 6;                                                 \
    const int bm = blockIdx.y * 128, bn = blockIdx.x * 128;                    \
    const int wr = (wid >> 1) * 64, wc = (wid & 1) * 64;                       \
    const int half = wid & 1;                                                  \
    const unsigned short* gsrc = (wid < 2) ? A_ : B_;                          \
    unsigned short* ldst0 = ((wid < 2) ? sA[0] : sB[0]) + half * 4096;         \
    unsigned short* ldst1 = ((wid < 2) ? sA[1] : sB[1]) + half * 4096;         \
    const int brow = ((wid < 2) ? bm : bn) + half * 64;                        \
    const int r8_  = lane >> 3;                                                \
    const int colb_ = ((lane & 7) ^ r8_) << 3;                                 \
    const size_t rowbase = (size_t)(brow + r8_) * K_ + colb_;                  \
    f32x4 acc[4][4];                                                           \
    _Pragma("unroll")                                                          \
    for (int m = 0; m < 4; ++m)                                                \
        _Pragma("unroll")                                                      \
        for (int n = 0; n < 4; ++n)                                            \
            acc[m][n] = f32x4{0.f, 0.f, 0.f, 0.f};                             \
    {                                                                          \
        const unsigned short* g = gsrc + rowbase;                              \
        _Pragma("unroll")                                                      \
        for (int c = 0; c < 8; ++c)                                            \
            gld_lds16(g + (size_t)c * 8 * K_, ldst0 + c * 512);                \
    }                                                                          \
    __syncthreads();                                                           \
    int pb = 0;                                                                \
    for (int k0 = 0; k0 < K_; k0 += 64) {                                      \
        if (k0 + 64 < K_) {                                                    \
            const unsigned short* g = gsrc + rowbase + k0 + 64;                \
            unsigned short* ld = pb ? ldst0 : ldst1;                           \
            _Pragma("unroll")                                                  \
            for (int c = 0; c < 8; ++c)                                        \
                gld_lds16(g + (size_t)c * 8 * K_, ld + c * 512);               \
        }                                                                      \
        const unsigned short* cA = pb ? sA[1] : sA[0];                         \
        const unsigned short* cB = pb ? sB[1] : sB[0];                         \
        _Pragma("unroll")                                                      \
        for (int ks2 = 0; ks2 < 2; ++ks2) {                                    \
            const int e8 = (lane >> 4) + ks2 * 4;                              \
            bf16x8 a[4], b[4];                                                 \
            _Pragma("unroll")                                                  \
            for (int m = 0; m < 4; ++m)                                        \
                a[m] = lds_frag(cA, wr + m * 16 + (lane & 15), e8);            \
            _Pragma("unroll")                                                  \
            for (int n = 0; n < 4; ++n)                                        \
                b[n] = lds_frag(cB, wc + n * 16 + (lane & 15), e8);            \
            _Pragma("unroll")                                                  \
            for (int m = 0; m < 4; ++m)                                        \
                _Pragma("unroll")                                              \
                for (int n = 0; n < 4; ++n)                                    \
                    acc[m][n] = __builtin_amdgcn_mfma_f32_16x16x32_bf16(       \
                        a[m], b[n], acc[m][n], 0, 0, 0);                       \
        }                                                                      \
        __syncthreads();                                                       \
        pb ^= 1;                                                               \
    }

// out-projection: f32 C with bias
__global__ __launch_bounds__(256) void gemm_mfma_out(
    const unsigned short* __restrict__ A, const unsigned short* __restrict__ B,
    const float* __restrict__ bias, float* __restrict__ C, int M, int N, int K)
{
    GEMM_CORE(A, B, K)
    #pragma unroll
    for (int n = 0; n < 4; ++n) {
        const int col = bn + wc + n * 16 + (lane & 15);
        const float bv = bias[col];
        #pragma unroll
        for (int m = 0; m < 4; ++m) {
            const int row0 = bm + wr + m * 16 + (lane >> 4) * 4;
            #pragma unroll
            for (int j = 0; j < 4; ++j)
                C[(size_t)(row0 + j) * N + col] = acc[m][n][j] + bv;
        }
    }
}

// QKV projection: scatter epilogue into single bf16 planes
//   Q [b,h,s,d] pre-scaled by log2(e)/8, K [b,h,s,d], Vt [b,h,d,s]
// V-class stores packed: 4 consecutive s -> one ushort4.
__global__ __launch_bounds__(256) void gemm_mfma_qkv(
    const unsigned short* __restrict__ A, const unsigned short* __restrict__ B,
    const float* __restrict__ bias,
    unsigned short* __restrict__ Qs, unsigned short* __restrict__ Ks,
    unsigned short* __restrict__ Vt, int M, int N, int K)
{
    GEMM_CORE(A, B, K)
    #pragma unroll
    for (int n = 0; n < 4; ++n) {
        const int col = bn + wc + n * 16 + (lane & 15);
        const unsigned head = (unsigned)col / 192u;
        const int c = col - (int)head * 192;
        const int cls = c >> 6;                    // 0=q 1=k 2=v (uniform per n)
        const float bv = bias[col];
        #pragma unroll
        for (int m = 0; m < 4; ++m) {
            const int row0 = bm + wr + m * 16 + (lane >> 4) * 4;
            if (cls == 2) {
                const int bb = row0 >> 11, ss = row0 & 2047;
                unsigned short vv[4];
                #pragma unroll
                for (int j = 0; j < 4; ++j) vv[j] = bf16_rne(acc[m][n][j] + bv);
                *(ushort4*)&Vt[((size_t)(bb * NHEADS + head) * HDIM + (c - 128)) * S_LEN + ss] =
                    make_ushort4(vv[0], vv[1], vv[2], vv[3]);
            } else {
                #pragma unroll
                for (int j = 0; j < 4; ++j) {
                    const int row = row0 + j;
                    const int bb = row >> 11, ss = row & 2047;
                    float val = acc[m][n][j] + bv;
                    if (cls == 0) val *= 0.18033688011110918f;  // (1/8)*log2(e)
                    const size_t idx = ((size_t)(bb * NHEADS + head) * S_LEN + ss) * HDIM + (c & 63);
                    if (cls == 0) Qs[idx] = bf16_rne(val); else Ks[idx] = bf16_rne(val);
                }
            }
        }
    }
}

// ---------------------------------------------------------------------------
// Full-bf16 MFMA flash attention, kv-split, double-buffered. PROVEN R7/R10
// numerics: online max (tree), defer-max THR=8, exp2-domain softmax
// (Q pre-scaled by log2e/8), l via mfma(ones,P), m-weighted parity merge.
// Grid: 512 blocks x 8 waves; par=wid>>2 kv parity; wq=wid&3 owns 32 q-cols.
// ---------------------------------------------------------------------------
__global__ __launch_bounds__(512) void attn_mfma_kernel(
    const unsigned short* __restrict__ Qs, const unsigned short* __restrict__ Ks,
    const unsigned short* __restrict__ Vt, unsigned short* __restrict__ ob)
{
    __shared__ unsigned short smem[2][2][2][4096];   // [buf][par][cls][64*64]

    const int tid  = threadIdx.x;
    const int lane = tid & 63;
    const int wid  = tid >> 6;         // 0..7
    const int wq   = wid & 3;          // q sub-tile (32 cols)
    const int par  = wid >> 2;         // kv parity
    const int h    = lane >> 5;        // k-octet half
    const int qcol = lane & 31;

    // XCD-chunked remap: 512 blocks, XCD = bid%8 gets a contiguous 64-chunk
    const int bid = blockIdx.x;
    const int lb  = (bid & 7) * 64 + (bid >> 3);
    const int qt  = lb & 15;
    const int bh  = lb >> 4;
    const int q0  = qt * 128 + wq * 32;

    // ---- Q fragments in registers (pre-scaled at GEMM1) ----
    bf16x8 qf[4];
    {
        const unsigned short* qr = Qs + ((size_t)bh * S_LEN + q0 + qcol) * HDIM + h * 8;
        #pragma unroll
        for (int ks = 0; ks < 4; ++ks) qf[ks] = *(const bf16x8*)(qr + ks * 16);
    }

    // ones A-operand for the l-sum MFMA (bf16 1.0 = 0x3F80)
    bf16x8 onesv;
    #pragma unroll
    for (int i = 0; i < 8; ++i) onesv[i] = (short)0x3F80;

    // ---- staging: wave stages half a plane (4KB = 4 chunks) ----
    const unsigned short* gKV = (wq < 2) ? Ks : Vt;
    const int cls   = wq >> 1;                       // 0=K, 1=V
    const int cbase = (wq & 1) * 4;                  // chunk range
    const int r8    = lane >> 3;                     // row within 8-row chunk
    const int colb  = ((lane & 7) ^ r8) << 3;        // inverse-swizzled col

    float m_run = -1e30f;
    f32x16 accO[2];
    f32x16 accL;
    #pragma unroll
    for (int r = 0; r < 16; ++r) { accO[0][r] = 0.0f; accO[1][r] = 0.0f; accL[r] = 0.0f; }

    #define STAGE(buf, kt)                                                          \
        do {                                                                        \
            unsigned short* pl_ = &smem[buf][par][cls][0];                          \
            if (cls == 0) {                                                         \
                const unsigned short* g_ = gKV + ((size_t)bh * S_LEN + (kt) + r8) * HDIM + colb; \
                _Pragma("unroll")                                                   \
                for (int c_ = 0; c_ < 4; ++c_)                                      \
                    gld_lds16(g_ + (size_t)(cbase + c_) * 8 * HDIM,                 \
                              pl_ + (cbase + c_) * 512);                            \
            } else {                                                                \
                const unsigned short* g_ = gKV + ((size_t)bh * HDIM + r8) * S_LEN + (kt) + colb; \
                _Pragma("unroll")                                                   \
                for (int c_ = 0; c_ < 4; ++c_)                                      \
                    gld_lds16(g_ + (size_t)(cbase + c_) * 8 * S_LEN,                \
                              pl_ + (cbase + c_) * 512);                            \
            }                                                                       \
        } while (0)

    STAGE(0, par * 64);
    __syncthreads();

    int cur = 0;
    for (int it = 0; it < S_LEN / 128; ++it) {       // 16 iterations
        if (it + 1 < S_LEN / 128) STAGE(cur ^ 1, (it + 1) * 128 + par * 64);

        const unsigned short* cK = &smem[cur][par][0][0];
        const unsigned short* cV = &smem[cur][par][1][0];

        // ---- S^T = K . Q^T : accS[mm] is 32kv x 32q, lane owns q=qcol ----
        f32x16 accS[2];
        #pragma unroll
        for (int r = 0; r < 16; ++r) { accS[0][r] = 0.0f; accS[1][r] = 0.0f; }

        __builtin_amdgcn_s_setprio(1);
        #pragma unroll
        for (int ks = 0; ks < 4; ++ks) {
            const int e8 = ks * 2 + h;
            #pragma unroll
            for (int mm = 0; mm < 2; ++mm) {
                bf16x8 ak = lds_frag(cK, mm * 32 + qcol, e8);
                accS[mm] = __builtin_amdgcn_mfma_f32_32x32x16_bf16(ak, qf[ks], accS[mm], 0, 0, 0);
            }
        }
        __builtin_amdgcn_s_setprio(0);

        // ---- online softmax (exp2 domain): max tree, defer-max, in-place exp
        float t16[16];
        #pragma unroll
        for (int i = 0; i < 16; ++i) t16[i] = fmaxf(accS[0][i], accS[1][i]);
        float t8[8];
        #pragma unroll
        for (int i = 0; i < 8; ++i) t8[i] = fmaxf(t16[i], t16[i + 8]);
        float t4[4];
        #pragma unroll
        for (int i = 0; i < 4; ++i) t4[i] = fmaxf(t8[i], t8[i + 4]);
        float mx = fmaxf(fmaxf(t4[0], t4[1]), fmaxf(t4[2], t4[3]));
        mx = fmaxf(mx, __shfl_xor(mx, 32));

        if (!__all(mx <= m_run + 8.0f)) {
            const float mnew = fmaxf(m_run, mx);
            const float corr = __builtin_amdgcn_exp2f(m_run - mnew);
            m_run = mnew;
            #pragma unroll
            for (int r = 0; r < 16; ++r) {
                accO[0][r] *= corr; accO[1][r] *= corr; accL[r] *= corr;
            }
        }

        #pragma unroll
        for (int mm = 0; mm < 2; ++mm)
            #pragma unroll
            for (int r = 0; r < 16; ++r)
                accS[mm][r] = __builtin_amdgcn_exp2f(accS[mm][r] - m_run);

        // ---- P^T -> bf16 B-fragments (cvt_pk + shfl_xor(32)); PV + l-MFMA --
        const bool hib = (h != 0);
        #pragma unroll
        for (int mm = 0; mm < 2; ++mm) {
            u32 wh_[8], sh_[8];
            #pragma unroll
            for (int i = 0; i < 8; ++i) {
                const float pe = accS[mm][2 * i], po = accS[mm][2 * i + 1];
                asm("v_cvt_pk_bf16_f32 %0, %1, %2" : "=v"(wh_[i]) : "v"(pe), "v"(po));
            }
            #pragma unroll
            for (int i = 0; i < 8; ++i) sh_[i] = __shfl_xor(wh_[i], 32);
            #pragma unroll
            for (int cc = 0; cc < 2; ++cc) {
                const int b0 = cc * 4;
                union { u32 w[4]; bf16x8 v; } uh;
                uh.w[0] = hib ? sh_[b0 + 2] : wh_[b0 + 0];
                uh.w[1] = hib ? sh_[b0 + 3] : wh_[b0 + 1];
                uh.w[2] = hib ? wh_[b0 + 2] : sh_[b0 + 0];
                uh.w[3] = hib ? wh_[b0 + 3] : sh_[b0 + 1];
                const int e8 = (mm * 2 + cc) * 2 + h;   // kv octet
                bf16x8 vf0 = lds_frag(cV, qcol, e8);
                bf16x8 vf1 = lds_frag(cV, 32 + qcol, e8);
                accO[0] = __builtin_amdgcn_mfma_f32_32x32x16_bf16(vf0, uh.v, accO[0], 0, 0, 0);
                accO[1] = __builtin_amdgcn_mfma_f32_32x32x16_bf16(vf1, uh.v, accO[1], 0, 0, 0);
                accL    = __builtin_amdgcn_mfma_f32_32x32x16_bf16(onesv, uh.v, accL, 0, 0, 0);
            }
        }

        __syncthreads();   // cur reads done + next stage (vmcnt) drained
        cur ^= 1;
    }
    #undef STAGE

    const float l_run = accL[0];   // all 16 components identical

    // ---- merge parity pair states via LDS, then epilogue (par 0 writes) ----
    float* mbuf = (float*)&smem[0][0][0][0];
    if (par == 1) {
        float* dst = mbuf + ((size_t)(wq * 64 + lane)) * 35;  // stride 35: conflict-free
        #pragma unroll
        for (int mdc = 0; mdc < 2; ++mdc)
            #pragma unroll
            for (int r = 0; r < 16; ++r) dst[mdc * 16 + r] = accO[mdc][r];
        dst[32] = m_run;
        dst[33] = l_run;
    }
    __syncthreads();
    if (par == 0) {
        const float* src = mbuf + ((size_t)(wq * 64 + lane)) * 35;
        const float m2 = src[32], l2 = src[33];
        const float mt = fmaxf(m_run, m2);
        const float w1 = __builtin_amdgcn_exp2f(m_run - mt);
        const float w2 = __builtin_amdgcn_exp2f(m2 - mt);
        const float inv = 1.0f / (l_run * w1 + l2 * w2);

        const int bb = bh >> 4, hh = bh & 15;
        const int ss = q0 + qcol;
        unsigned short* po = ob + ((size_t)(bb * S_LEN + ss)) * D_MODEL + hh * HDIM;
        #pragma unroll
        for (int mdc = 0; mdc < 2; ++mdc)
            #pragma unroll
            for (int r = 0; r < 16; r += 2) {
                const int d = mdc * 32 + (r & 3) + 8 * (r >> 2) + 4 * h;
                const float v0 = (accO[mdc][r]     * w1 + src[mdc * 16 + r]     * w2) * inv;
                const float v1 = (accO[mdc][r + 1] * w1 + src[mdc * 16 + r + 1] * w2) * inv;
                *(u32*)(po + d) = ((u32)bf16_rne(v1) << 16) | bf16_rne(v0);
            }
    }
}

// ---------------------------------------------------------------------------
extern "C" void kernel_launch(void* const* d_in, const int* in_sizes, int n_in,
                              void* d_out, int out_size, void* d_ws, size_t ws_size,
                              hipStream_t stream)
{
    const float* x     = (const float*)d_in[0];
    const float* w_qkv = (const float*)d_in[1];
    const float* b_qkv = (const float*)d_in[2];
    const float* w_out = (const float*)d_in[3];
    const float* b_out = (const float*)d_in[4];
    float* out = (float*)d_out;

    const int M = NBATCH * S_LEN;  // 4096
    const size_t PL = (size_t)32 * S_LEN * HDIM;   // 4,194,304 elems

    // ws layout (50.3 MB of >= 67 MB). xb/wqb/wob contiguous (fused cast).
    unsigned short* xb  = (unsigned short*)d_ws;           // 4M elems
    unsigned short* wqb = xb  + PL;                        // 3M
    unsigned short* wob = wqb + (size_t)DQKV * D_MODEL;    // 1M
    unsigned short* Qs  = wob + (size_t)D_MODEL * D_MODEL; // 4M
    unsigned short* Ks  = Qs  + PL;
    unsigned short* Vt  = Ks  + PL;
    unsigned short* aob = Vt  + PL;                        // 4M

    dim3 blk(256);
    cast_all_bf16<<<1024, blk, 0, stream>>>(x, w_qkv, w_out, xb);

    gemm_mfma_qkv<<<dim3(DQKV / 128, M / 128), blk, 0, stream>>>(
        xb, wqb, b_qkv, Qs, Ks, Vt, M, DQKV, D_MODEL);

    attn_mfma_kernel<<<dim3(512), dim3(512), 0, stream>>>(Qs, Ks, Vt, aob);

    gemm_mfma_out<<<dim3(D_MODEL / 128, M / 128), blk, 0, stream>>>(
        aob, wob, b_out, out, M, D_MODEL, D_MODEL);
}